// Round 11
// baseline (372.390 us; speedup 1.0000x reference)
//
#include <hip/hip_runtime.h>
#include <hip/hip_bf16.h>
#include <hip/hip_cooperative_groups.h>

namespace cg = cooperative_groups;

#define BATCH 8
#define NN    2048
#define FIN   512
#define FOUT  32
#define GALPHA 0.2f
#define NROW  128         // n-rows per main-phase block
#define NIT   32          // 2048/64 k-intervals

typedef float  f32x4  __attribute__((ext_vector_type(4)));
typedef __bf16 bf16x8 __attribute__((ext_vector_type(8)));
typedef unsigned short u16;
typedef u16 u16x8 __attribute__((ext_vector_type(8)));

static __device__ __forceinline__ u16 f2bf(float f) {
    __hip_bfloat16 h = __float2bfloat16(f);
    union { __hip_bfloat16 h; u16 u; } c; c.h = h; return c.u;
}
static __device__ __forceinline__ float bf2f(u16 u) {
    union { u16 u; __hip_bfloat16 h; } c; c.u = u; return __bfloat162float(c.h);
}

// Fused cooperative kernel: grid 256 x 512, 1 block/CU (co-resident).
// PHASE 1 (prep, R4-verified bodies re-widthed to 512 thr): block = (b, mt)
//   owns 64 rows; loops all 8 i-chunks {x->bf16 transpose to xt, f1/f2 dot
//   accumulated in REGISTERS (plain store — no atomics, no memset), adj
//   bit-pack (LDS-staged, bit layout identical to verified k_pack)}.
// grid.sync()
// PHASE 2 (main, VERBATIM R4 k_main): fused attn-gen + GEMM + softmax + ELU.
// Rationale: cross-round accounting shows ~50 µs of inter-dispatch gaps in
// the 5-dispatch chain; this removes 2 dispatches + the f1 memset + atomics
// while keeping both phases' proven structures byte-equivalent.
__global__ __launch_bounds__(512, 2) void k_fused(
    const float* __restrict__ x, const int* __restrict__ adj,
    const float* __restrict__ Wfc, const float* __restrict__ Wat,
    __hip_bfloat16* __restrict__ xt,
    float* __restrict__ f1, float* __restrict__ f2,
    unsigned int* __restrict__ bits,
    float* __restrict__ out)
{
    // LDS pool (33280 B):
    //   prep : [0,9216) tile | [9216,11264) w1s | [11264,13312) w2s | [13312,29696) pls
    //   main : [0,32768) At[2][128*64] u16 | [32768,33280) rs[128]
    __shared__ __align__(16) char smem[33280];
    const int tt = threadIdx.x;           // 0..511

    // ================= PHASE 1: prep =================
    {
        const int b  = blockIdx.x >> 5;   // 0..7
        const int mt = blockIdx.x & 31;   // 0..31
        const int m0 = mt * 64;
        u16 (*tile)[72]   = (u16(*)[72])smem;
        float* w1s        = (float*)(smem + 9216);
        float* w2s        = (float*)(smem + 11264);
        unsigned int* pls = (unsigned int*)(smem + 13312);

        // w1/w2 for ALL 512 i, once per block (Wfc 64 KB, L2-broadcast)
        {
            float s1 = 0.f, s2 = 0.f;
            #pragma unroll
            for (int o = 0; o < FOUT; o++) {
                float wv = Wfc[o * FIN + tt];
                s1 += wv * Wat[o];
                s2 += wv * Wat[FOUT + o];
            }
            w1s[tt] = s1; w2s[tt] = s2;
        }
        __syncthreads();

        const int mm  = tt >> 3;          // 0..63 (1 row/thread)
        const int icl = (tt & 7) * 8;     // 0..56
        float f1a = 0.f, f2a = 0.f;       // lane-local partials across chunks

        for (int it = 0; it < 8; it++) {
            const int i0 = it * 64;
            // x load + bf16 pack + f-dot partials
            const f32x4* src = (const f32x4*)(x + ((size_t)(b * NN + m0 + mm)) * FIN + i0 + icl);
            f32x4 v0 = src[0], v1 = src[1];
            f32x4 wA = *(const f32x4*)&w1s[i0 + icl];
            f32x4 wB = *(const f32x4*)&w1s[i0 + icl + 4];
            f32x4 wC = *(const f32x4*)&w2s[i0 + icl];
            f32x4 wD = *(const f32x4*)&w2s[i0 + icl + 4];
            u16x8 pk;
            float s1 = 0.f, s2 = 0.f;
            #pragma unroll
            for (int j = 0; j < 4; j++) {
                pk[j] = f2bf(v0[j]); pk[4 + j] = f2bf(v1[j]);
                s1 += v0[j] * wA[j] + v1[j] * wB[j];
                s2 += v0[j] * wC[j] + v1[j] * wD[j];
            }
            f1a += s1; f2a += s2;
            *(u16x8*)&tile[mm][icl] = pk;
            __syncthreads();
            // transpose-out (same (ii,mc) set as R4, 1 pass at 512 thr)
            {
                __hip_bfloat16* xtb = xt + ((size_t)b * FIN + i0) * NN + m0;
                const int ii = tt >> 3;       // 0..63
                const int mc = (tt & 7) * 8;
                u16x8 v;
                #pragma unroll
                for (int j = 0; j < 8; j++) v[j] = tile[mc + j][ii];
                *(u16x8*)(xtb + (size_t)ii * NN + mc) = v;
            }
            // adj pack rows [m0+it*8, +8): Phase A -> pls (contiguous loads)
            {
                const int* ab = adj + (size_t)(b * NN + m0 + it * 8) * NN;
                #pragma unroll
                for (int s = 0; s < 8; s++) {
                    int4 v = *(const int4*)(ab + (size_t)(s * 512 + tt) * 4);
                    unsigned int pb = (v.x != 0 ? 0x00000001u : 0u)
                                    | (v.y != 0 ? 0x00000100u : 0u)
                                    | (v.z != 0 ? 0x00010000u : 0u)
                                    | (v.w != 0 ? 0x01000000u : 0u);
                    pls[s * 512 + tt] = pb;
                }
            }
            __syncthreads();
            // Phase B: 8 rows x 64 words, 1 word/thread (verified bit layout)
            {
                const int r = tt >> 6, c = tt & 63;
                const unsigned int* q = pls + r * 512 + c * 8;
                unsigned int bv = 0;
                #pragma unroll
                for (int j = 0; j < 8; j++) {
                    unsigned int pb = q[j];
                    bv |= (pb         & 1u) << (j * 4 + 0);
                    bv |= ((pb >> 8)  & 1u) << (j * 4 + 1);
                    bv |= ((pb >> 16) & 1u) << (j * 4 + 2);
                    bv |= ((pb >> 24) & 1u) << (j * 4 + 3);
                }
                bits[(size_t)(b * NN + m0 + it * 8 + r) * 64 + c] = bv;
            }
            if (it < 7) __syncthreads();   // guard tile/pls reuse next chunk
        }
        // full-row reduce (8 lanes) + plain store — no atomics, no memset
        #pragma unroll
        for (int off = 1; off < 8; off <<= 1) {
            f1a += __shfl_xor(f1a, off);
            f2a += __shfl_xor(f2a, off);
        }
        if ((tt & 7) == 0) {
            f1[b * NN + m0 + mm] = f1a;
            f2[b * NN + m0 + mm] = f2a;
        }
    }

    __threadfence();
    cg::this_grid().sync();

    // ================= PHASE 2: main (VERBATIM R4 k_main) =================
    {
        const int bx = blockIdx.x;
        const int b = bx & 7, rt = (bx >> 3) & 15, it = bx >> 7;
        const int n0 = rt * NROW;
        const int i0 = it * 256;
        const int tid = tt;
        const int lane = tid & 63, wv = tid >> 6;
        const int quad = lane >> 4, l15 = lane & 15;

        u16* Atb  = (u16*)smem;                   // At[2][NROW*64], verified swizzle
        float* rs = (float*)(smem + 32768);

        // --- gen role: thread -> (row = tid>>2, m-quarter q4 = tid&3) ---
        const int grow = tid >> 2;           // 0..127
        const int q4   = tid & 3;
        const unsigned short* bp = (const unsigned short*)bits
                                   + ((size_t)(b * NN) + n0 + grow) * 128 + q4;  // +4 per interval
        const float* f2p = f2 + b * NN + q4 * 16;                                 // +64 per interval
        const float  f1v = f1[b * NN + n0 + grow];
        const int swz = grow & 7;
        u16* wp0 = Atb + grow * 64 + (((q4 * 2) ^ swz) * 8);
        u16* wp1 = Atb + grow * 64 + (((q4 * 2 + 1) ^ swz) * 8);
        float rpart = 0.f;

        // --- MFMA role: wave wv owns i-cols [i0 + wv*32, +32), 2 col-tiles ---
        const __hip_bfloat16* xtp = xt + ((size_t)(b * FIN) + i0 + wv * 32 + l15) * NN + quad * 8;

        f32x4 acc[8][2];
        #pragma unroll
        for (int s = 0; s < 8; s++) { acc[s][0] = (f32x4){0,0,0,0}; acc[s][1] = (f32x4){0,0,0,0}; }

        auto gen = [&](int buf, unsigned int bv, const f32x4* fr) {
            u16x8 pk0, pk1;
            #pragma unroll
            for (int e = 0; e < 16; e++) {
                float s  = f1v + fr[e >> 2][e & 3];
                float ls = fmaxf(s, GALPHA * s);                 // leaky_relu
                float ev = ((bv >> e) & 1u) ? __expf(ls) : 0.f;
                u16 hb = f2bf(ev);
                rpart += bf2f(hb);                               // rowsum of bf16-rounded
                if (e < 8) pk0[e] = hb; else pk1[e - 8] = hb;
            }
            *(u16x8*)(wp0 + buf * (NROW * 64)) = pk0;
            *(u16x8*)(wp1 + buf * (NROW * 64)) = pk1;
        };

        // prologue: gen tile 0; prime rings for tiles 1,2; B for t=0
        {
            unsigned int b0 = bp[0];
            f32x4 g0[4];
            #pragma unroll
            for (int j = 0; j < 4; j++) g0[j] = *(const f32x4*)(f2p + j * 4);
            gen(0, b0, g0);
        }
        unsigned int brng[2];
        f32x4 frng[2][4];
        brng[1] = bp[4];
        #pragma unroll
        for (int j = 0; j < 4; j++) frng[1][j] = *(const f32x4*)(f2p + 64 + j * 4);
        brng[0] = bp[8];
        #pragma unroll
        for (int j = 0; j < 4; j++) frng[0][j] = *(const f32x4*)(f2p + 128 + j * 4);

        bf16x8 Bc[2][2], Bn[2][2];
        #pragma unroll
        for (int ks = 0; ks < 2; ks++)
            #pragma unroll
            for (int c = 0; c < 2; c++)
                Bc[ks][c] = *(const bf16x8*)(xtp + ks * 32 + (size_t)(c * 16) * NN);
        __syncthreads();

        #pragma unroll 2
        for (int t = 0; t < NIT; t++) {
            const int cur = t & 1;
            if (t < NIT - 1) {   // B prefetch for t+1 (consumed after next barrier)
                const __hip_bfloat16* xk = xtp + (t + 1) * 64;
                #pragma unroll
                for (int ks = 0; ks < 2; ks++)
                    #pragma unroll
                    for (int c = 0; c < 2; c++)
                        Bn[ks][c] = *(const bf16x8*)(xk + ks * 32 + (size_t)(c * 16) * NN);
            }
            #pragma unroll
            for (int ks = 0; ks < 2; ks++) {
                #pragma unroll
                for (int s = 0; s < 8; s++) {
                    const int row = s * 16 + l15;
                    bf16x8 Af = *(const bf16x8*)(Atb + cur * (NROW * 64)
                                  + row * 64 + (((ks * 4 + quad) ^ (row & 7)) * 8));
                    acc[s][0] = __builtin_amdgcn_mfma_f32_16x16x32_bf16(Af, Bc[ks][0], acc[s][0], 0, 0, 0);
                    acc[s][1] = __builtin_amdgcn_mfma_f32_16x16x32_bf16(Af, Bc[ks][1], acc[s][1], 0, 0, 0);
                }
            }
            if (t < NIT - 1) {
                gen(1 - cur, brng[(t + 1) & 1], frng[(t + 1) & 1]);   // tile t+1
                if (t < NIT - 2) {                                    // refill ring: tile t+2
                    brng[t & 1] = bp[(t + 2) * 4];
                    #pragma unroll
                    for (int j = 0; j < 4; j++)
                        frng[t & 1][j] = *(const f32x4*)(f2p + (t + 2) * 64 + j * 4);
                }
            }
            // LDS-only barrier: global prefetches stay in flight (no vmcnt drain)
            asm volatile("s_waitcnt lgkmcnt(0)\ns_barrier" ::: "memory");
            #pragma unroll
            for (int ks = 0; ks < 2; ks++) {
                Bc[ks][0] = Bn[ks][0]; Bc[ks][1] = Bn[ks][1];
            }
        }

        // rowsum: reduce over the 4 m-quarter threads of each row
        rpart += __shfl_xor(rpart, 1);
        rpart += __shfl_xor(rpart, 2);
        if (q4 == 0) rs[grow] = 1.0f / rpart;
        __syncthreads();

        // epilogue: normalize, ELU, store fp32
        #pragma unroll
        for (int s = 0; s < 8; s++) {
            #pragma unroll
            for (int r = 0; r < 4; r++) {
                const int row = s * 16 + quad * 4 + r;
                const float inv = rs[row];
                float* op = out + ((size_t)b * NN + (n0 + row)) * FIN + i0 + wv * 32 + l15;
                #pragma unroll
                for (int c = 0; c < 2; c++) {
                    float v = acc[s][c][r] * inv;
                    v = v > 0.f ? v : (__expf(v) - 1.f);   // elu
                    op[c * 16] = v;
                }
            }
        }
    }
}

extern "C" void kernel_launch(void* const* d_in, const int* in_sizes, int n_in,
                              void* d_out, int out_size, void* d_ws, size_t ws_size,
                              hipStream_t stream) {
    const float* x   = (const float*)d_in[0];
    const int*   adj = (const int*)d_in[1];
    const float* Wfc = (const float*)d_in[2];
    const float* Wat = (const float*)d_in[3];
    float* out = (float*)d_out;

    float* f1 = (float*)d_ws;                                   // 16384
    float* f2 = f1 + BATCH * NN;                                // 16384
    unsigned int* bits = (unsigned int*)(f2 + BATCH * NN);      // 16384*64 u32 = 4.2 MB
    __hip_bfloat16* xt = (__hip_bfloat16*)(bits + (size_t)BATCH * NN * 64);  // 16.8 MB

    void* args[] = { (void*)&x, (void*)&adj, (void*)&Wfc, (void*)&Wat,
                     (void*)&xt, (void*)&f1, (void*)&f2, (void*)&bits, (void*)&out };
    hipLaunchCooperativeKernel((const void*)k_fused, dim3(256), dim3(512),
                               args, 0, stream);
}

// Round 12
// 284.137 us; speedup vs baseline: 1.3106x; 1.3106x over previous
//
#include <hip/hip_runtime.h>
#include <hip/hip_bf16.h>

#define BATCH 8
#define NN    2048
#define FIN   512
#define FOUT  32
#define GALPHA 0.2f
#define NROW  128         // n-rows per k_main block
#define NIT   32          // 2048/64 k-intervals

typedef float  f32x4  __attribute__((ext_vector_type(4)));
typedef __bf16 bf16x8 __attribute__((ext_vector_type(8)));
typedef unsigned short u16;
typedef u16 u16x8 __attribute__((ext_vector_type(8)));

static __device__ __forceinline__ u16 f2bf(float f) {
    __hip_bfloat16 h = __float2bfloat16(f);
    union { __hip_bfloat16 h; u16 u; } c; c.h = h; return c.u;
}
static __device__ __forceinline__ float bf2f(u16 u) {
    union { u16 u; __hip_bfloat16 h; } c; c.u = u; return __bfloat162float(c.h);
}

// K_prep v4 (FINAL — best of five measured prep schedules, 77-81 µs each):
// grid 2048 x 256 — one block per (b, mt, it) 64x64 chunk. w1/w2 inlined;
// xtf transpose + f1/f2 atomics; LDS-staged contiguous adj pack (bit layout
// identical to the original verified k_pack).
// Falsified alternatives: 256-block fused (R1, latency-bound), strip-load
// pack (R2), issue-early adj (R7), cooperative re-width (R11, bank conflicts).
__global__ __launch_bounds__(256) void k_prep(
    const float* __restrict__ x, const int* __restrict__ adj,
    const float* __restrict__ Wfc, const float* __restrict__ Wat,
    __hip_bfloat16* __restrict__ xt,
    float* __restrict__ f1, float* __restrict__ f2,
    unsigned int* __restrict__ bits)
{
    const int bx = blockIdx.x;
    const int it = bx & 7, mt = (bx >> 3) & 31, b = bx >> 8;
    const int m0 = mt * 64, i0 = it * 64;
    const int tt = threadIdx.x;

    __shared__ __align__(16) char smem[16384];
    u16 (*tile)[72]   = (u16(*)[72])smem;
    float* w1s        = (float*)(smem + 9216);
    float* w2s        = (float*)(smem + 9216 + 256);
    unsigned int* pls = (unsigned int*)smem;

    if (tt < 64) {
        const int i = i0 + tt;
        float s1 = 0.f, s2 = 0.f;
        #pragma unroll
        for (int o = 0; o < FOUT; o++) {
            float wv = Wfc[o * FIN + i];
            s1 += wv * Wat[o];
            s2 += wv * Wat[FOUT + o];
        }
        w1s[tt] = s1; w2s[tt] = s2;
    }
    __syncthreads();

    const int mm  = tt >> 3;         // 0..31
    const int icl = (tt & 7) * 8;    // 0..56
    const float* xb = x + ((size_t)b * NN + m0) * FIN + i0;
    f32x4 wA = *(const f32x4*)&w1s[icl];
    f32x4 wB = *(const f32x4*)&w1s[icl + 4];
    f32x4 wC = *(const f32x4*)&w2s[icl];
    f32x4 wD = *(const f32x4*)&w2s[icl + 4];
    float p1[2], p2[2];
    #pragma unroll
    for (int h = 0; h < 2; h++) {
        int m = mm + h * 32;
        const f32x4* src = (const f32x4*)(xb + (size_t)m * FIN + icl);
        f32x4 v0 = src[0], v1 = src[1];
        u16x8 pk;
        float s1 = 0.f, s2 = 0.f;
        #pragma unroll
        for (int j = 0; j < 4; j++) {
            pk[j] = f2bf(v0[j]); pk[4 + j] = f2bf(v1[j]);
            s1 += v0[j] * wA[j] + v1[j] * wB[j];
            s2 += v0[j] * wC[j] + v1[j] * wD[j];
        }
        p1[h] = s1; p2[h] = s2;
        *(u16x8*)&tile[m][icl] = pk;
    }
    #pragma unroll
    for (int off = 1; off < 8; off <<= 1) {
        p1[0] += __shfl_xor(p1[0], off); p1[1] += __shfl_xor(p1[1], off);
        p2[0] += __shfl_xor(p2[0], off); p2[1] += __shfl_xor(p2[1], off);
    }
    if ((tt & 7) == 0) {
        size_t r0 = (size_t)b * NN + m0 + mm;
        atomicAdd(&f1[r0], p1[0]);      atomicAdd(&f1[r0 + 32], p1[1]);
        atomicAdd(&f2[r0], p2[0]);      atomicAdd(&f2[r0 + 32], p2[1]);
    }
    __syncthreads();
    __hip_bfloat16* xtb = xt + ((size_t)b * FIN + i0) * NN + m0;
    const int mc = (tt & 7) * 8;
    #pragma unroll
    for (int h = 0; h < 2; h++) {
        int ii = (tt >> 3) + h * 32;
        u16x8 v;
        #pragma unroll
        for (int j = 0; j < 8; j++) v[j] = tile[mc + j][ii];
        *(u16x8*)(xtb + (size_t)ii * NN + mc) = v;
    }

    __syncthreads();   // tile LDS is dead; reuse as predicate staging
    {
        const int* ab = adj + (size_t)(b * NN + m0 + it * 8) * NN;
        #pragma unroll
        for (int s = 0; s < 16; s++) {
            int4 v = *(const int4*)(ab + (size_t)(s * 256 + tt) * 4);
            unsigned int pb = (v.x != 0 ? 0x00000001u : 0u)
                            | (v.y != 0 ? 0x00000100u : 0u)
                            | (v.z != 0 ? 0x00010000u : 0u)
                            | (v.w != 0 ? 0x01000000u : 0u);
            pls[s * 256 + tt] = pb;
        }
        __syncthreads();
        const int r = tt >> 5, c0 = tt & 31;
        #pragma unroll
        for (int half = 0; half < 2; half++) {
            const int c = c0 + half * 32;
            const unsigned int* q = pls + r * 512 + c * 8;
            unsigned int bv = 0;
            #pragma unroll
            for (int j = 0; j < 8; j++) {
                unsigned int pb = q[j];
                bv |= (pb         & 1u) << (j * 4 + 0);
                bv |= ((pb >> 8)  & 1u) << (j * 4 + 1);
                bv |= ((pb >> 16) & 1u) << (j * 4 + 2);
                bv |= ((pb >> 24) & 1u) << (j * 4 + 3);
            }
            bits[(size_t)(b * NN + m0 + it * 8 + r) * 64 + c] = bv;
        }
    }
}

// K3 (FINAL — verified optimum of seven tested structures): fused attn-gen
// + GEMM + softmax-normalize + ELU. grid 256 = 16 rt x 2 it x 8 b (b = bx&7
// -> XCD affinity). 512 thr / 8 waves. Block: 128 rows x 256 cols; BK=64.
// Falsified alternatives: 2-blocks/CU row-split (R5), barrier-free lane-
// local gen (R6), col-split 2-blocks/CU (R8), it=1 gen-once (R9),
// cooperative fusion (R11 — loses fill/kernel overlap). The per-t LDS-only
// barrier + 2-deep gen ring + B-reg prefetch at 1 block/CU is the optimum.
__global__ __launch_bounds__(512, 2) void k_main(
    const unsigned int* __restrict__ bits, const __hip_bfloat16* __restrict__ xt,
    const float* __restrict__ f1, const float* __restrict__ f2,
    float* __restrict__ out)
{
    const int bx = blockIdx.x;
    const int b = bx & 7, rt = (bx >> 3) & 15, it = bx >> 7;
    const int n0 = rt * NROW;
    const int i0 = it * 256;
    const int tid = threadIdx.x;
    const int lane = tid & 63, wv = tid >> 6;
    const int quad = lane >> 4, l15 = lane & 15;

    // A tile: [row][octet ^ (row&7)] u16, row stride 64 (128B) — verified swizzle.
    __shared__ u16 At[2][NROW * 64];     // 2 x 16 KB
    __shared__ float rs[NROW];

    // --- gen role: thread -> (row = tid>>2, m-quarter q4 = tid&3, 16 m each) ---
    const int grow = tid >> 2;           // 0..127
    const int q4   = tid & 3;
    const unsigned short* bp = (const unsigned short*)bits
                               + ((size_t)(b * NN) + n0 + grow) * 128 + q4;  // +4 per interval
    const float* f2p = f2 + b * NN + q4 * 16;                                 // +64 per interval
    const float  f1v = f1[b * NN + n0 + grow];
    const int swz = grow & 7;
    u16* wp0 = &At[0][grow * 64 + (((q4 * 2) ^ swz) * 8)];
    u16* wp1 = &At[0][grow * 64 + (((q4 * 2 + 1) ^ swz) * 8)];
    float rpart = 0.f;

    // --- MFMA role: wave wv owns i-cols [i0 + wv*32, +32), 2 col-tiles ---
    const __hip_bfloat16* xtp = xt + ((size_t)(b * FIN) + i0 + wv * 32 + l15) * NN + quad * 8;

    f32x4 acc[8][2];
    #pragma unroll
    for (int s = 0; s < 8; s++) { acc[s][0] = (f32x4){0,0,0,0}; acc[s][1] = (f32x4){0,0,0,0}; }

    auto gen = [&](int buf, unsigned int bv, const f32x4* fr) {
        u16x8 pk0, pk1;
        #pragma unroll
        for (int e = 0; e < 16; e++) {
            float s  = f1v + fr[e >> 2][e & 3];
            float ls = fmaxf(s, GALPHA * s);                 // leaky_relu
            float ev = ((bv >> e) & 1u) ? __expf(ls) : 0.f;
            u16 hb = f2bf(ev);
            rpart += bf2f(hb);                               // rowsum of bf16-rounded
            if (e < 8) pk0[e] = hb; else pk1[e - 8] = hb;
        }
        *(u16x8*)(wp0 + buf * (NROW * 64)) = pk0;
        *(u16x8*)(wp1 + buf * (NROW * 64)) = pk1;
    };

    // prologue: gen tile 0 (direct loads); prime rings for tiles 1,2; B for t=0
    {
        unsigned int b0 = bp[0];
        f32x4 g0[4];
        #pragma unroll
        for (int j = 0; j < 4; j++) g0[j] = *(const f32x4*)(f2p + j * 4);
        gen(0, b0, g0);
    }
    unsigned int brng[2];
    f32x4 frng[2][4];
    brng[1] = bp[4];
    #pragma unroll
    for (int j = 0; j < 4; j++) frng[1][j] = *(const f32x4*)(f2p + 64 + j * 4);
    brng[0] = bp[8];
    #pragma unroll
    for (int j = 0; j < 4; j++) frng[0][j] = *(const f32x4*)(f2p + 128 + j * 4);

    bf16x8 Bc[2][2], Bn[2][2];
    #pragma unroll
    for (int ks = 0; ks < 2; ks++)
        #pragma unroll
        for (int c = 0; c < 2; c++)
            Bc[ks][c] = *(const bf16x8*)(xtp + ks * 32 + (size_t)(c * 16) * NN);
    __syncthreads();

    #pragma unroll 2
    for (int t = 0; t < NIT; t++) {
        const int cur = t & 1;
        if (t < NIT - 1) {   // B prefetch for t+1 (consumed after next barrier)
            const __hip_bfloat16* xk = xtp + (t + 1) * 64;
            #pragma unroll
            for (int ks = 0; ks < 2; ks++)
                #pragma unroll
                for (int c = 0; c < 2; c++)
                    Bn[ks][c] = *(const bf16x8*)(xk + ks * 32 + (size_t)(c * 16) * NN);
        }
        #pragma unroll
        for (int ks = 0; ks < 2; ks++) {
            #pragma unroll
            for (int s = 0; s < 8; s++) {
                const int row = s * 16 + l15;
                bf16x8 Af = *(const bf16x8*)&At[cur][row * 64 + (((ks * 4 + quad) ^ (row & 7)) * 8)];
                acc[s][0] = __builtin_amdgcn_mfma_f32_16x16x32_bf16(Af, Bc[ks][0], acc[s][0], 0, 0, 0);
                acc[s][1] = __builtin_amdgcn_mfma_f32_16x16x32_bf16(Af, Bc[ks][1], acc[s][1], 0, 0, 0);
            }
        }
        if (t < NIT - 1) {
            gen(1 - cur, brng[(t + 1) & 1], frng[(t + 1) & 1]);   // tile t+1
            if (t < NIT - 2) {                                    // refill ring: tile t+2
                brng[t & 1] = bp[(t + 2) * 4];
                #pragma unroll
                for (int j = 0; j < 4; j++)
                    frng[t & 1][j] = *(const f32x4*)(f2p + (t + 2) * 64 + j * 4);
            }
        }
        // LDS-only barrier: global prefetches stay in flight (no vmcnt drain)
        asm volatile("s_waitcnt lgkmcnt(0)\ns_barrier" ::: "memory");
        #pragma unroll
        for (int ks = 0; ks < 2; ks++) {
            Bc[ks][0] = Bn[ks][0]; Bc[ks][1] = Bn[ks][1];
        }
    }

    // rowsum: reduce over the 4 m-quarter threads of each row
    rpart += __shfl_xor(rpart, 1);
    rpart += __shfl_xor(rpart, 2);
    if (q4 == 0) rs[grow] = 1.0f / rpart;
    __syncthreads();

    // epilogue: normalize, ELU, store fp32
    #pragma unroll
    for (int s = 0; s < 8; s++) {
        #pragma unroll
        for (int r = 0; r < 4; r++) {
            const int row = s * 16 + quad * 4 + r;
            const float inv = rs[row];
            float* op = out + ((size_t)b * NN + (n0 + row)) * FIN + i0 + wv * 32 + l15;
            #pragma unroll
            for (int c = 0; c < 2; c++) {
                float v = acc[s][c][r] * inv;
                v = v > 0.f ? v : (__expf(v) - 1.f);   // elu
                op[c * 16] = v;
            }
        }
    }
}

extern "C" void kernel_launch(void* const* d_in, const int* in_sizes, int n_in,
                              void* d_out, int out_size, void* d_ws, size_t ws_size,
                              hipStream_t stream) {
    const float* x   = (const float*)d_in[0];
    const int*   adj = (const int*)d_in[1];
    const float* Wfc = (const float*)d_in[2];
    const float* Wat = (const float*)d_in[3];
    float* out = (float*)d_out;

    float* f1 = (float*)d_ws;                                   // 16384
    float* f2 = f1 + BATCH * NN;                                // 16384
    unsigned int* bits = (unsigned int*)(f2 + BATCH * NN);      // 16384*64 u32 = 4.2 MB
    __hip_bfloat16* xt = (__hip_bfloat16*)(bits + (size_t)BATCH * NN * 64);  // 16.8 MB

    hipMemsetAsync(f1, 0, (size_t)2 * BATCH * NN * sizeof(float), stream);
    hipLaunchKernelGGL(k_prep, dim3(2048), dim3(256), 0, stream,
                       x, adj, Wfc, Wat, xt, f1, f2, bits);
    hipLaunchKernelGGL(k_main, dim3(256),  dim3(512), 0, stream,
                       bits, xt, f1, f2, out);
}